// Round 1
// 83.813 us; speedup vs baseline: 1.0428x; 1.0428x over previous
//
#include <hip/hip_runtime.h>
#include <math.h>

// R7: transpose the scatter loop — wave-per-point, lane-per-bin.
//
// Theory: R4-R6's inner loop issued one ds_add_f32 per lane-bin with 64
// SCATTERED addresses per wave op (each lane walks its own point's bin
// window). Scattered-address LDS atomic RMW serializes per bank/address;
// at 2 waves/SIMD nothing hides the DS backpressure -> ~40us for ~3us of
// VALU issue. Here each wave broadcasts one point's params via v_readlane
// (register-only) and its 64 lanes cover CONSECUTIVE bins: ds_add_f32 at
// 64 consecutive floats = 2-way bank aliasing = free (m136). Exponential
// is evaluated directly per bin (1 v_exp), removing the recurrence drift.
//
// Math identical to R4-R6 (absmax 0.0 there):
//  - w = aw + bw*diff, bw > 0; saturate clips w<=0 to exact 0 (lower cutoff).
//  - above r0 + 8*sigma: e <= 2^-46 -> skipped, mass << 1e-12 absolute.
//  - upper clip at 1.0 provably inactive (pdf*D/2 <= 0.48) -> intensity folds.

#define NBINS 512
#define TPB 1024               // 16 waves/block, 1 block/CU (vs 8 before)
#define NBLK 256
#define K_SQRT_HALF_PI 0.3989422804014327f   // sqrt(0.5/pi)
#define LOG2E 1.4426950408889634f

__device__ __forceinline__ float fast_exp2(float x) {
#if __has_builtin(__builtin_amdgcn_exp2f)
    return __builtin_amdgcn_exp2f(x);
#else
    return exp2f(x);
#endif
}

__device__ __forceinline__ int rdlane_i(int v, int l) {
#if __has_builtin(__builtin_amdgcn_readlane)
    return __builtin_amdgcn_readlane(v, l);
#else
    return __shfl(v, l, 64);
#endif
}
__device__ __forceinline__ float rdlane_f(float v, int l) {
    return __int_as_float(rdlane_i(__float_as_int(v), l));
}

__global__ __launch_bounds__(TPB) void gauss_scatter(
    const float* __restrict__ means,
    const float* __restrict__ scan_point,
    const float* __restrict__ colours,
    const float* __restrict__ coeffs,
    const float* __restrict__ opac,
    const float* __restrict__ scales,
    const int* __restrict__ view_id,
    float* __restrict__ out,
    int n)
{
    __shared__ float hist[NBINS];
    const int t = threadIdx.x;
    if (t < NBINS) hist[t] = 0.f;
    __syncthreads();

    const int vid = view_id[0];                  // VIEW_NUM == 1
    const float sx = scan_point[0], sy = scan_point[1], sz = scan_point[2];

    const int lane = t & 63;
    const int wid  = t >> 6;                     // 0..15
    // transposed chunk->wave mapping: chunk = wid*NBLK + blockIdx keeps all
    // 256 blocks ~equally loaded (12-13 active waves each) instead of
    // leaving blocks 196..255 idle.
    const int chunk   = wid * NBLK + blockIdx.x;
    const int nchunks = (n + 63) >> 6;

    // ---- phase A: per-lane point params (vectorized, coalesced) ----
    float r0 = 0.f, nna = 0.f, aw = 0.f, bw = 0.f;
    int lo = 0, num = 0;                         // num = 0 -> skip slot
    if (chunk < nchunks) {
        const int p = (chunk << 6) + lane;
        if (p < n) {
            float dx = means[3 * p + 0] - sx;
            float dy = means[3 * p + 1] - sy;
            float dz = means[3 * p + 2] - sz;
            r0 = sqrtf(fmaf(dx, dx, fmaf(dy, dy, dz * dz)));
            float sg = fmaxf(expf(scales[p]), 0.005f);   // max(exp(scales), BIN_RES/2)
            float inv_s = 1.0f / sg;
            float coeff = 1.0f / (1.0f + expf(-coeffs[p]));
            float op  = opac[p + vid];
            float col = colours[p];
            float ia  = (op * op) * (col * col) * 0.005f; // intensity * BIN_RES/2
            nna = -0.5f * LOG2E * inv_s * inv_s;          // exp2-units, negative
            aw  = ia * coeff * K_SQRT_HALF_PI * inv_s;    // pdf1 weight
            bw  = ia * (1.0f - coeff) * inv_s * inv_s;    // pdf2 weight (>0)
            float rlo = r0 - aw / bw;                     // exact w<=0 cutoff
            float rhi = fmaf(8.0f, sg, r0);               // e <= 2^-46 above
            int l = (int)floorf(rlo * 200.f) - 1;         // bin b: r = 0.005*(b+1)
            int h = (int)floorf(rhi * 200.f);
            l = l < 0 ? 0 : l;
            h = h > NBINS - 1 ? NBINS - 1 : h;
            lo  = l;
            num = (h >= l) ? (h - l + 1) : 0;
        }
    }

    // ---- phase B: wave-cooperative scatter, one point (slot) at a time ----
    for (int k = 0; k < 64; ++k) {
        const int num_k = rdlane_i(num, k);      // uniform -> s_cbranch skip
        if (num_k <= 0) continue;
        const int   lo_k  = rdlane_i(lo, k);
        const float r0_k  = rdlane_f(r0, k);
        const float nna_k = rdlane_f(nna, k);
        const float aw_k  = rdlane_f(aw, k);
        const float bw_k  = rdlane_f(bw, k);

        int b = lo_k + lane;                     // lane-consecutive bins
        const int bend = lo_k + num_k;           // exclusive
        float rb = 0.005f * (float)(b + 1);
        for (; b < bend; b += 64, rb += 0.32f) { // usually 1-2 rounds
            float diff = rb - r0_k;
            float e = fast_exp2((nna_k * diff) * diff);
            float w = fmaf(bw_k, diff, aw_k);
            atomicAdd(&hist[b], __saturatef(e * w));  // ds_add_f32, 2-way bank = free
        }
    }
    __syncthreads();

    // merge: staggered by one cache line (16 bins) per block so concurrent
    // blocks hit different L2 lines (R6 tuning, kept verbatim).
    if (t < NBINS) {
        const int bin = (t + (blockIdx.x << 4)) & (NBINS - 1);
        float h = hist[bin];
        if (h != 0.f) {
            float r = 0.005f * (float)(bin + 1);
            atomicAdd(&out[bin], h / (r * r));   // fold /r^DECAY (DECAY=2)
        }
    }
}

extern "C" void kernel_launch(void* const* d_in, const int* in_sizes, int n_in,
                              void* d_out, int out_size, void* d_ws, size_t ws_size,
                              hipStream_t stream) {
    const float* means = (const float*)d_in[0];
    const float* scan  = (const float*)d_in[1];
    const float* col   = (const float*)d_in[2];
    const float* cf    = (const float*)d_in[3];
    const float* op    = (const float*)d_in[4];
    const float* sc    = (const float*)d_in[5];
    const int*   vid   = (const int*)d_in[6];
    float* out = (float*)d_out;

    const int n = in_sizes[2];                   // colours: NUM_POINTS
    hipMemsetAsync(d_out, 0, (size_t)out_size * sizeof(float), stream);
    gauss_scatter<<<NBLK, TPB, 0, stream>>>(means, scan, col, cf, op, sc, vid, out, n);
}